// Round 12
// baseline (128.864 us; speedup 1.0000x reference)
//
#include <hip/hip_runtime.h>
#include <hip/hip_bf16.h>
#include <stdint.h>

// ---------------------------------------------------------------------------
// BinaryMLP fused, round 12: 32x32x16 MFMA + SINGLE broadcast LUT.
// New analysis: the kernel is LDS-read-pipe bound (all 8 waves redundantly
// read the same 64x32 activation slice every kt; ~1280 LDS cyc/CU-kt vs
// ~320 MFMA cyc/SIMD-kt -> matches measured 137us). 32x32x16 halves B bytes
// per FLOP. R9 tried this but bundled the replicated LUT, which R10 isolated
// as +7.7M conflicts on its own -> R9's regression was misattributed.
// This round = R9 (layouts correctness-verified) + single broadcast LUT
// (equal nibbles -> same address -> HW broadcast, free) + K1P=800.
// Schedule: L1 per-kt LDS dbuf w/ lgkm-only barriers (vmcnt never drained),
// L2/L3 barrier-free w/ depth-4 mask prefetch, setprio around MFMA clusters.
// ---------------------------------------------------------------------------

typedef __attribute__((ext_vector_type(8)))  short short8;   // 8 bf16
typedef __attribute__((ext_vector_type(4)))  float f32x4;
typedef __attribute__((ext_vector_type(16))) float f32x16;   // 32x32 accum

#define THREADS 512
#define BM      64
#define HID     512
#define K1      784
#define K1P     800             // 25 K-tiles of 32
#define BK      32
#define NK1     (K1P / BK)      // 25
#define NK2     (HID / BK)      // 16

// mask layout per layer: [wave][kt][lane] dwords (256 B per wave-kt)
#define M1_OFF  0
#define M1_BYTES (8 * NK1 * 256)            // 51200
#define M2_OFF  (M1_OFF + M1_BYTES)
#define M2_BYTES (8 * NK2 * 256)            // 32768
#define M3_OFF  (M2_OFF + M2_BYTES)
#define W4_OFF  (M3_OFF + M2_BYTES)
#define W4_BYTES (16 * HID * 2)             // 16384 (rows 10..15 zero)
#define WS_BYTES (W4_OFF + W4_BYTES)

#define H_BYTES  (BM * HID * 2)             // 65536
#define XBUF0    H_BYTES
#define XTILE_SZ (BM * BK * 2)              // 4096 per K-tile
#define LUT_OFF  (XBUF0 + 2 * XTILE_SZ)     // 73728 (128-aligned)
#define LDS_TOTAL (LUT_OFF + 128)           // 73856 -> 2 blocks/CU

#define LGKM0_BARRIER()  do {                                   \
    asm volatile("s_waitcnt lgkmcnt(0)" ::: "memory");          \
    __builtin_amdgcn_s_barrier();                               \
} while (0)

__device__ __forceinline__ unsigned short bfu(float f) {
    __hip_bfloat16 h = __float2bfloat16(f);
    return *reinterpret_cast<unsigned short*>(&h);
}

__device__ __forceinline__ unsigned cvtpk(float lo, float hi) {
    unsigned d;
    asm("v_cvt_pk_bf16_f32 %0, %1, %2" : "=v"(d) : "v"(lo), "v"(hi));
    return d;
}

// ---------------------------------------------------------------------------
// prep: pack sign bits in 32x32x16-fragment order:
// bit f*8+j (f = nt*2+ks): n = wave*64 + nt*32 + (lane&31),
//                          k = kt*32 + ks*16 + (lane>>5)*8 + j.
// w4 -> bf16 [16][512] panel (rows 10..15 zero).
// (Verified correct end-to-end by round 9's passing run, absmax 128.)
// ---------------------------------------------------------------------------
__global__ void prep_weights(const float* __restrict__ w1, const float* __restrict__ w2,
                             const float* __restrict__ w3, const float* __restrict__ w4,
                             unsigned char* __restrict__ ws)
{
    int id = blockIdx.x * blockDim.x + threadIdx.x;
    const int T1 = 8 * NK1 * 64;        // 12800
    const int T2 = 8 * NK2 * 64;        // 8192
    const int T4 = 16 * (HID / 16);     // 512

    if (id < T1) {
        int wn = id / (NK1 * 64), rem = id % (NK1 * 64);
        int kt = rem / 64, lane = rem % 64;
        int r32 = lane & 31, g32 = lane >> 5;
        unsigned m = 0;
#pragma unroll
        for (int f = 0; f < 4; ++f) {                  // f = nt*2 + ks
            int n = wn * 64 + (f >> 1) * 32 + r32;
            int kb = kt * BK + (f & 1) * 16 + g32 * 8;
#pragma unroll
            for (int j = 0; j < 8; ++j) {
                int k = kb + j;
                if (k < K1 && w1[n * K1 + k] < 0.0f) m |= 1u << (f * 8 + j);
            }
        }
        *(unsigned*)(ws + M1_OFF + (size_t)id * 4) = m;
        return;
    }
    id -= T1;
    if (id < 2 * T2) {
        const float* w = (id < T2) ? w2 : w3;
        unsigned base = (id < T2) ? M2_OFF : M3_OFF;
        int iid = (id < T2) ? id : id - T2;
        int wn = iid / (NK2 * 64), rem = iid % (NK2 * 64);
        int kt = rem / 64, lane = rem % 64;
        int r32 = lane & 31, g32 = lane >> 5;
        unsigned m = 0;
#pragma unroll
        for (int f = 0; f < 4; ++f) {
            int n = wn * 64 + (f >> 1) * 32 + r32;
            int kb = kt * BK + (f & 1) * 16 + g32 * 8;
#pragma unroll
            for (int j = 0; j < 8; ++j)
                if (w[n * HID + kb + j] < 0.0f) m |= 1u << (f * 8 + j);
        }
        *(unsigned*)(ws + base + (size_t)iid * 4) = m;
        return;
    }
    id -= 2 * T2;
    if (id < T4) {
        int n = id / (HID / 16), j = id % (HID / 16);
        int kp0 = j * 16;
        unsigned short v[16];
#pragma unroll
        for (int i = 0; i < 16; ++i)
            v[i] = (n < 10) ? bfu(w4[n * HID + kp0 + i]) : 0;
        unsigned off = W4_OFF + n * 1024 + kp0 * 2;   // plain [16][512]
        *(short8*)(ws + off)      = *(short8*)&v[0];
        *(short8*)(ws + off + 16) = *(short8*)&v[8];
    }
}

// ---------------------------------------------------------------------------
// fused MLP: 1 block = 64 batch rows, 8 waves each owning 64 output cols
// ---------------------------------------------------------------------------
__global__ __launch_bounds__(THREADS, 4)
void fused_mlp(const float* __restrict__ x,
               const unsigned char* __restrict__ ws,
               const float* __restrict__ b1, const float* __restrict__ b2,
               const float* __restrict__ b3, const float* __restrict__ b4,
               float* __restrict__ out)
{
    extern __shared__ unsigned char lds[];
    const int tid  = threadIdx.x;
    const int lane = tid & 63;
    const int wave = tid >> 6;           // 0..7 : N-slice of 64 cols
    const int lr   = lane & 15;          // 16x16 decomposition (L4 only)
    const int lg   = lane >> 4;
    const int l31  = lane & 31;          // 32x32 decomposition
    const int l5   = lane >> 5;
    const int row_base = blockIdx.x * BM;
    const unsigned swz = (unsigned)((lane & 7) << 4);   // == (l31&7)<<4

    // sign LUT (SINGLE, broadcast): nibble -> 4 bf16 (+1/-1), 8 B per entry.
    // Equal nibbles across lanes hit the SAME address -> HW broadcast, free.
    if (tid < 16) {
        unsigned e0 = ((tid & 1) ? 0xBF80u : 0x3F80u)
                    | (((tid & 2) ? 0xBF80u : 0x3F80u) << 16);
        unsigned e1 = ((tid & 4) ? 0xBF80u : 0x3F80u)
                    | (((tid & 8) ? 0xBF80u : 0x3F80u) << 16);
        uint2 e; e.x = e0; e.y = e1;
        *(uint2*)(lds + LUT_OFF + tid * 8) = e;
    }

    // acc[nt][bt]: 32 n-cols (nt) x 32 batch rows (bt)
    f32x16 acc00, acc01, acc10, acc11;
    auto zeroAcc = [&]() {
        f32x16 z;
#pragma unroll
        for (int i = 0; i < 16; ++i) z[i] = 0.f;
        acc00 = z; acc01 = z; acc10 = z; acc11 = z;
    };

    auto h_off = [&](int row, int bc) -> unsigned {
        return ((unsigned)(row * 1024 + bc)) ^ (unsigned)((row & 7) << 4);
    };

    // expand one 8-bit fragment via broadcast LUT -> short8 (4 VGPR)
    auto lutA = [&](unsigned m, int f) -> short8 {
        unsigned lo = (m >> (f * 8)) & 15u;
        unsigned hi = (m >> (f * 8 + 4)) & 15u;
        union { short8 s; uint2 d[2]; } r;
        r.d[0] = *(const uint2*)(lds + LUT_OFF + lo * 8);
        r.d[1] = *(const uint2*)(lds + LUT_OFF + hi * 8);
        return r.s;
    };

    // epilogue one acc tile: relu(acc+bias) -> bf16 quads -> ds_write_b64
    // D: batch row = bt*32 + l31; n = wave*64 + nt*32 + 8*q + 4*l5 + (reg&3)
    auto epi = [&](const f32x16& a, int nt, int bt, const float* __restrict__ bias) {
        const int brow = bt * 32 + l31;
#pragma unroll
        for (int q = 0; q < 4; ++q) {
            int n0 = wave * 64 + nt * 32 + 8 * q + 4 * l5;
            float4 bv = *(const float4*)(bias + n0);
            float v0 = a[4 * q + 0] + bv.x; v0 = v0 > 0.f ? v0 : 0.f;
            float v1 = a[4 * q + 1] + bv.y; v1 = v1 > 0.f ? v1 : 0.f;
            float v2 = a[4 * q + 2] + bv.z; v2 = v2 > 0.f ? v2 : 0.f;
            float v3 = a[4 * q + 3] + bv.w; v3 = v3 > 0.f ? v3 : 0.f;
            uint2 d; d.x = cvtpk(v0, v1); d.y = cvtpk(v2, v3);
            unsigned off = ((unsigned)(brow * 1024 + n0 * 2)) ^ (unsigned)((brow & 7) << 4);
            *(uint2*)(lds + off) = d;
        }
    };
    auto epilogueToH = [&](const float* __restrict__ bias) {
        epi(acc00, 0, 0, bias); epi(acc01, 0, 1, bias);
        epi(acc10, 1, 0, bias); epi(acc11, 1, 1, bias);
    };

#define MFMA32(A, B, C) C = __builtin_amdgcn_mfma_f32_32x32x16_bf16(A, B, C, 0, 0, 0)

    // ---------------- Layer 1: x (per-kt LDS dbuf) -> h1 -------------------
    {
        zeroAcc();
        const unsigned char* mb1 = ws + M1_OFF + wave * (NK1 * 256) + lane * 4;
        const int srow = tid >> 3, sq = tid & 7;   // staging: 8 lanes/row
        const float* xrow = x + (size_t)(row_base + srow) * K1;
        const unsigned s_off = (((unsigned)(srow * 64 + sq * 8)) ^ (unsigned)((srow & 7) << 4)) + XBUF0;
        // B-read offsets within an x tile (row = bt*32+l31, kcol = ks*32+l5*16)
        // +32 (ks) overlaps XOR bits -> kept INSIDE the XOR; +2048/+4096 carry-free
        const unsigned x00 = (((unsigned)(l31 * 64 + l5 * 16)) ^ swz) + XBUF0;        // bt0 ks0
        const unsigned x01 = (((unsigned)(l31 * 64 + 32 + l5 * 16)) ^ swz) + XBUF0;   // bt0 ks1

        auto xload = [&](int t) -> float4 {
            int col = t * BK + sq * 4;
            return (col < K1) ? *(const float4*)(xrow + col)
                              : make_float4(0.f, 0.f, 0.f, 0.f);
        };
        auto stage_write = [&](int buf, float4 v) {
            uint2 pk; pk.x = cvtpk(v.x, v.y); pk.y = cvtpk(v.z, v.w);
            *(uint2*)(lds + s_off + buf * XTILE_SZ) = pk;
        };
        auto mload1 = [&](int t) -> unsigned {
            int tc = t < NK1 ? t : NK1 - 1;
            return *(const unsigned*)(mb1 + tc * 256);
        };
        auto l1_compute = [&](int buf, unsigned m) {
            unsigned b0 = x00 + buf * XTILE_SZ, b1 = x01 + buf * XTILE_SZ;
            short8 B00 = *(const short8*)(lds + b0);
            short8 B01 = *(const short8*)(lds + b1);
            short8 B10 = *(const short8*)(lds + b0 + 2048);
            short8 B11 = *(const short8*)(lds + b1 + 2048);
            short8 A00 = lutA(m, 0), A01 = lutA(m, 1);
            short8 A10 = lutA(m, 2), A11 = lutA(m, 3);
            __builtin_amdgcn_s_setprio(1);
            MFMA32(A00, B00, acc00); MFMA32(A01, B01, acc00);
            MFMA32(A00, B10, acc01); MFMA32(A01, B11, acc01);
            MFMA32(A10, B00, acc10); MFMA32(A11, B01, acc10);
            MFMA32(A10, B10, acc11); MFMA32(A11, B11, acc11);
            __builtin_amdgcn_s_setprio(0);
        };

        // prologue: tile0 staged; tiles 1,2 in regs; masks 0,1 in regs
        stage_write(0, xload(0));
        float4 xc = xload(1), xn = xload(2);
        unsigned mc = mload1(0), mn = mload1(1);
        LGKM0_BARRIER();        // also publishes the LUT

#pragma unroll 1
        for (int kt = 0; kt < NK1; ++kt) {
            float4 xnew = xload(kt + 3);
            unsigned mnew = mload1(kt + 2);
            l1_compute(kt & 1, mc);
            stage_write((kt + 1) & 1, xc);
            xc = xn; xn = xnew; mc = mn; mn = mnew;
            LGKM0_BARRIER();
        }

        epilogueToH(b1);           // H untouched until here
        LGKM0_BARRIER();           // h1 visible
    }

    // ---------------- Layers 2 & 3: barrier-free, masks depth-4 ------------
#pragma unroll 1
    for (int layer = 0; layer < 2; ++layer) {
        const unsigned char* mb = ws + (layer == 0 ? M2_OFF : M3_OFF)
                                + wave * (NK2 * 256) + lane * 4;
        const float* bias = (layer == 0) ? b2 : b3;

        zeroAcc();

        auto mload2 = [&](int t) -> unsigned {
            int tc = t < NK2 ? t : NK2 - 1;
            return *(const unsigned*)(mb + tc * 256);
        };
        auto l23_compute = [&](int kt, unsigned m) {
            // kt*64 and ks*32 overlap the XOR field -> INSIDE the XOR (R7 lesson)
            unsigned h0 = (((unsigned)(l31 * 1024 + kt * 64 + l5 * 16)) ^ swz);
            unsigned h1 = (((unsigned)(l31 * 1024 + kt * 64 + 32 + l5 * 16)) ^ swz);
            short8 B00 = *(const short8*)(lds + h0);
            short8 B01 = *(const short8*)(lds + h1);
            short8 B10 = *(const short8*)(lds + h0 + 32768);   // bt=1, carry-free
            short8 B11 = *(const short8*)(lds + h1 + 32768);
            short8 A00 = lutA(m, 0), A01 = lutA(m, 1);
            short8 A10 = lutA(m, 2), A11 = lutA(m, 3);
            __builtin_amdgcn_s_setprio(1);
            MFMA32(A00, B00, acc00); MFMA32(A01, B01, acc00);
            MFMA32(A00, B10, acc01); MFMA32(A01, B11, acc01);
            MFMA32(A10, B00, acc10); MFMA32(A11, B01, acc10);
            MFMA32(A10, B10, acc11); MFMA32(A11, B11, acc11);
            __builtin_amdgcn_s_setprio(0);
        };

        unsigned q0 = mload2(0), q1 = mload2(1), q2 = mload2(2), q3 = mload2(3);
#pragma unroll 1
        for (int kt = 0; kt < NK2; kt += 4) {
            l23_compute(kt + 0, q0); q0 = mload2(kt + 4);
            l23_compute(kt + 1, q1); q1 = mload2(kt + 5);
            l23_compute(kt + 2, q2); q2 = mload2(kt + 6);
            l23_compute(kt + 3, q3); q3 = mload2(kt + 7);
        }

        LGKM0_BARRIER();           // all waves' H reads done before overwrite
        epilogueToH(bias);
        LGKM0_BARRIER();           // new H visible
    }

    // ---------------- Layer 4: h3 @ w4^T (16-col padded, 10 real) ----------
    if (wave < 4) {
        const unsigned char* w4b = ws + W4_OFF + lr * 1024 + lg * 16;
        const int m = wave * 16 + lr;
        short8 w4f[16];
#pragma unroll
        for (int kt = 0; kt < NK2; ++kt)
            w4f[kt] = *(const short8*)(w4b + kt * 64);
        f32x4 acc4 = (f32x4){0.f, 0.f, 0.f, 0.f};
#pragma unroll
        for (int kt = 0; kt < NK2; ++kt) {
            short8 a = *(const short8*)(lds + h_off(m, kt * 64 + lg * 16));
            acc4 = __builtin_amdgcn_mfma_f32_16x16x32_bf16(a, w4f[kt], acc4, 0, 0, 0);
        }
        if (lr < 10) {
            float bv = b4[lr];
#pragma unroll
            for (int r = 0; r < 4; ++r) {
                int row = row_base + wave * 16 + lg * 4 + r;
                out[(size_t)row * 10 + lr] = acc4[r] + bv;
            }
        }
    }
#undef MFMA32
}

extern "C" void kernel_launch(void* const* d_in, const int* in_sizes, int n_in,
                              void* d_out, int out_size, void* d_ws, size_t ws_size,
                              hipStream_t stream) {
    const float* x  = (const float*)d_in[0];
    const float* w1 = (const float*)d_in[1];
    const float* b1 = (const float*)d_in[2];
    const float* w2 = (const float*)d_in[3];
    const float* b2 = (const float*)d_in[4];
    const float* w3 = (const float*)d_in[5];
    const float* b3 = (const float*)d_in[6];
    const float* w4 = (const float*)d_in[7];
    const float* b4 = (const float*)d_in[8];
    float* out = (float*)d_out;
    unsigned char* ws = (unsigned char*)d_ws;

    if (ws_size < (size_t)WS_BYTES) return;

    const int B = in_sizes[0] / K1;           // 65536
    const int nblk = B / BM;                  // 1024

    (void)hipFuncSetAttribute((const void*)fused_mlp,
                              hipFuncAttributeMaxDynamicSharedMemorySize, LDS_TOTAL);

    const int prep_total = 8 * NK1 * 64 + 2 * (8 * NK2 * 64) + 16 * (HID / 16);
    prep_weights<<<(prep_total + 255) / 256, 256, 0, stream>>>(w1, w2, w3, w4, ws);
    fused_mlp<<<nblk, THREADS, LDS_TOTAL, stream>>>(x, ws, b1, b2, b3, b4, out);
}

// Round 13
// 105.845 us; speedup vs baseline: 1.2175x; 1.2175x over previous
//
#include <hip/hip_runtime.h>
#include <hip/hip_bf16.h>
#include <stdint.h>

// ---------------------------------------------------------------------------
// BinaryMLP fused — FINAL (round-11 verified best, 110.0 us).
// Design: binarized weights packed as 1-bit masks (prep kernel), expanded
// in-kernel to bf16 +-1 MFMA A-fragments via a single broadcast 16-entry LDS
// LUT; activations live in a 64x512 bf16 XOR-swizzled LDS tile (H), updated
// in place layer by layer; epilogue via v_cvt_pk_bf16_f32 + ds_write_b64.
// Schedule: L1 per-kt LDS dbuf for x with lgkm-only barriers (vmcnt is NEVER
// drained anywhere); L2/L3 K-loops barrier-free with depth-4 mask prefetch;
// setprio(1) around MFMA clusters. BM=64, 8 waves x (64n x 64b), 2 blocks/CU.
//
// Measured-negative variants (do not retry): 32x32x16 MFMA (R9/R12: same
// LDS-per-FLOP due to fragment reuse, longer dep chains); LUT replication
// (R10: breaks same-address broadcast, 9.3M->17M conflicts); B-register
// double-buffer or depth-4 W prefetch (R4/R10: spills past 128 VGPR ->
// GB-scale scratch traffic); W or x staged via per-K-step LDS + vmcnt(0)
// barriers (R1/R3: barrier drain serializes ~full memory latency per kt).
// XOR-swizzle rule (R7 bug): any offset term overlapping the swizzle bits
// must be applied INSIDE the XOR; (a^s)+d != (a+d)^s when d hits bits 4..6.
// ---------------------------------------------------------------------------

typedef __attribute__((ext_vector_type(8))) short short8;   // 8 bf16
typedef __attribute__((ext_vector_type(4))) float f32x4;    // MFMA accum

#define THREADS 512
#define BM      64
#define HID     512
#define K1      784
#define K1P     800             // 25 K-tiles of 32
#define BK      32
#define NK1     (K1P / BK)      // 25
#define NK2     (HID / BK)      // 16

// mask layout per layer: [wave][kt][lane] dwords (256 B per wave-kt)
#define M1_OFF  0
#define M1_BYTES (8 * NK1 * 256)            // 51200
#define M2_OFF  (M1_OFF + M1_BYTES)
#define M2_BYTES (8 * NK2 * 256)            // 32768
#define M3_OFF  (M2_OFF + M2_BYTES)
#define W4_OFF  (M3_OFF + M2_BYTES)
#define W4_BYTES (16 * HID * 2)             // 16384 (rows 10..15 zero)
#define WS_BYTES (W4_OFF + W4_BYTES)

#define H_BYTES  (BM * HID * 2)             // 65536
#define XBUF0    H_BYTES
#define XTILE_SZ (BM * BK * 2)              // 4096 per K-tile
#define LUT_OFF  (XBUF0 + 2 * XTILE_SZ)     // 73728 (128-aligned)
#define LDS_TOTAL (LUT_OFF + 128)           // 73856 -> 2 blocks/CU

#define LGKM0_BARRIER()  do {                                   \
    asm volatile("s_waitcnt lgkmcnt(0)" ::: "memory");          \
    __builtin_amdgcn_s_barrier();                               \
} while (0)

__device__ __forceinline__ unsigned short bfu(float f) {
    __hip_bfloat16 h = __float2bfloat16(f);
    return *reinterpret_cast<unsigned short*>(&h);
}

__device__ __forceinline__ unsigned cvtpk(float lo, float hi) {
    unsigned d;
    asm("v_cvt_pk_bf16_f32 %0, %1, %2" : "=v"(d) : "v"(lo), "v"(hi));
    return d;
}

// ---------------------------------------------------------------------------
// prep: pack sign bits in per-(wave,kt,lane) fragment order (bit nf*8+j:
// n = wave*64+nf*16+(lane&15), k = kt*32+(lane>>4)*8+j); w4 -> bf16 panel.
// ---------------------------------------------------------------------------
__global__ void prep_weights(const float* __restrict__ w1, const float* __restrict__ w2,
                             const float* __restrict__ w3, const float* __restrict__ w4,
                             unsigned char* __restrict__ ws)
{
    int id = blockIdx.x * blockDim.x + threadIdx.x;
    const int T1 = 8 * NK1 * 64;        // 12800
    const int T2 = 8 * NK2 * 64;        // 8192
    const int T4 = 16 * (HID / 16);     // 512

    if (id < T1) {
        int wn = id / (NK1 * 64), rem = id % (NK1 * 64);
        int kt = rem / 64, lane = rem % 64;
        int lr = lane & 15, lg = lane >> 4;
        unsigned m = 0;
#pragma unroll
        for (int nf = 0; nf < 4; ++nf) {
            int n = wn * 64 + nf * 16 + lr;
#pragma unroll
            for (int j = 0; j < 8; ++j) {
                int k = kt * BK + lg * 8 + j;
                if (k < K1 && w1[n * K1 + k] < 0.0f) m |= 1u << (nf * 8 + j);
            }
        }
        *(unsigned*)(ws + M1_OFF + (size_t)id * 4) = m;
        return;
    }
    id -= T1;
    if (id < 2 * T2) {
        const float* w = (id < T2) ? w2 : w3;
        unsigned base = (id < T2) ? M2_OFF : M3_OFF;
        int iid = (id < T2) ? id : id - T2;
        int wn = iid / (NK2 * 64), rem = iid % (NK2 * 64);
        int kt = rem / 64, lane = rem % 64;
        int lr = lane & 15, lg = lane >> 4;
        unsigned m = 0;
#pragma unroll
        for (int nf = 0; nf < 4; ++nf) {
            int n = wn * 64 + nf * 16 + lr;
#pragma unroll
            for (int j = 0; j < 8; ++j) {
                int k = kt * BK + lg * 8 + j;
                if (w[n * HID + k] < 0.0f) m |= 1u << (nf * 8 + j);
            }
        }
        *(unsigned*)(ws + base + (size_t)iid * 4) = m;
        return;
    }
    id -= 2 * T2;
    if (id < T4) {
        int n = id / (HID / 16), j = id % (HID / 16);
        int kp0 = j * 16;
        unsigned short v[16];
#pragma unroll
        for (int i = 0; i < 16; ++i)
            v[i] = (n < 10) ? bfu(w4[n * HID + kp0 + i]) : 0;
        unsigned off = W4_OFF + n * 1024 + kp0 * 2;   // plain [16][512]
        *(short8*)(ws + off)      = *(short8*)&v[0];
        *(short8*)(ws + off + 16) = *(short8*)&v[8];
    }
}

// ---------------------------------------------------------------------------
// fused MLP: 1 block = 64 batch rows, 8 waves each owning 64 output cols
// ---------------------------------------------------------------------------
__global__ __launch_bounds__(THREADS, 4)
void fused_mlp(const float* __restrict__ x,
               const unsigned char* __restrict__ ws,
               const float* __restrict__ b1, const float* __restrict__ b2,
               const float* __restrict__ b3, const float* __restrict__ b4,
               float* __restrict__ out)
{
    extern __shared__ unsigned char lds[];
    const int tid  = threadIdx.x;
    const int lane = tid & 63;
    const int wave = tid >> 6;           // 0..7 : N-slice of 64 cols
    const int lr   = lane & 15;
    const int lg   = lane >> 4;
    const int row_base = blockIdx.x * BM;
    const unsigned swz = (unsigned)((lr & 7) << 4);

    // sign LUT (SINGLE, broadcast-friendly): nibble -> 4 bf16 (+1/-1), 8 B/entry
    if (tid < 16) {
        unsigned e0 = ((tid & 1) ? 0xBF80u : 0x3F80u)
                    | (((tid & 2) ? 0xBF80u : 0x3F80u) << 16);
        unsigned e1 = ((tid & 4) ? 0xBF80u : 0x3F80u)
                    | (((tid & 8) ? 0xBF80u : 0x3F80u) << 16);
        uint2 e; e.x = e0; e.y = e1;
        *(uint2*)(lds + LUT_OFF + tid * 8) = e;
    }

    // acc[nf][mg]: MFMA tile = (weight cols nf*16, batch rows mg*16).
    // D layout (swapped operands): lane col = batch row (lane&15), lane row
    // quad = 4 consecutive n at n0 = wave*64 + nf*16 + lg*4.
    f32x4 acc[4][4];
    auto zeroAcc = [&]() {
#pragma unroll
        for (int nf = 0; nf < 4; ++nf)
#pragma unroll
            for (int mg = 0; mg < 4; ++mg)
                acc[nf][mg] = (f32x4){0.f, 0.f, 0.f, 0.f};
    };

    auto h_off = [&](int row, int bc) -> unsigned {
        return ((unsigned)(row * 1024 + bc)) ^ (unsigned)((row & 7) << 4);
    };

    // epilogue: relu(acc+bias) -> bf16 pairs (cvt_pk) -> ds_write_b64
    auto epilogueToH = [&](const float* __restrict__ bias) {
#pragma unroll
        for (int nf = 0; nf < 4; ++nf) {
            const int n0 = wave * 64 + nf * 16 + lg * 4;
            float4 bv = *(const float4*)(bias + n0);
#pragma unroll
            for (int mg = 0; mg < 4; ++mg) {
                float v0 = acc[nf][mg][0] + bv.x; v0 = v0 > 0.f ? v0 : 0.f;
                float v1 = acc[nf][mg][1] + bv.y; v1 = v1 > 0.f ? v1 : 0.f;
                float v2 = acc[nf][mg][2] + bv.z; v2 = v2 > 0.f ? v2 : 0.f;
                float v3 = acc[nf][mg][3] + bv.w; v3 = v3 > 0.f ? v3 : 0.f;
                uint2 d; d.x = cvtpk(v0, v1); d.y = cvtpk(v2, v3);
                int row = mg * 16 + lr;
                unsigned off = ((unsigned)(row * 1024 + n0 * 2)) ^ (unsigned)((row & 7) << 4);
                *(uint2*)(lds + off) = d;
            }
        }
    };

    // expand one 8-bit fragment via LUT (2 nibble lookups, broadcast) -> short8
    auto lutA = [&](unsigned m, int nf) -> short8 {
        unsigned lo = (m >> (nf * 8)) & 15u;
        unsigned hi = (m >> (nf * 8 + 4)) & 15u;
        union { short8 s; uint2 d[2]; } r;
        r.d[0] = *(const uint2*)(lds + LUT_OFF + lo * 8);
        r.d[1] = *(const uint2*)(lds + LUT_OFF + hi * 8);
        return r.s;
    };

    // ---------------- Layer 1: x (per-kt LDS dbuf) -> h1 -------------------
    {
        zeroAcc();
        const unsigned char* mb1 = ws + M1_OFF + wave * (NK1 * 256) + lane * 4;
        const int srow = tid >> 3, sq = tid & 7;   // staging: 8 lanes/row
        const float* xrow = x + (size_t)(row_base + srow) * K1;
        const unsigned s_off = (((unsigned)(srow * 64 + sq * 8)) ^ (unsigned)((srow & 7) << 4)) + XBUF0;
        // safe hoist: XOR'd term < 1024; +buf*4096 / +mf*1024 are carry-free
        const unsigned xbase = (((unsigned)(lr * 64 + lg * 16)) ^ swz) + XBUF0;

        auto xload = [&](int t) -> float4 {
            int col = t * BK + sq * 4;
            return (col < K1) ? *(const float4*)(xrow + col)
                              : make_float4(0.f, 0.f, 0.f, 0.f);
        };
        auto stage_write = [&](int buf, float4 v) {
            uint2 pk; pk.x = cvtpk(v.x, v.y); pk.y = cvtpk(v.z, v.w);
            *(uint2*)(lds + s_off + buf * XTILE_SZ) = pk;
        };
        auto mload1 = [&](int t) -> unsigned {
            int tc = t < NK1 ? t : NK1 - 1;
            return *(const unsigned*)(mb1 + tc * 256);
        };
        auto l1_compute = [&](int buf, unsigned m) {
            unsigned xb = xbase + buf * XTILE_SZ;
            short8 B0 = *(const short8*)(lds + xb);
            short8 B1 = *(const short8*)(lds + xb + 1024);
            short8 B2 = *(const short8*)(lds + xb + 2048);
            short8 B3 = *(const short8*)(lds + xb + 3072);
            __builtin_amdgcn_s_setprio(1);
#pragma unroll
            for (int nf = 0; nf < 4; ++nf) {
                short8 A = lutA(m, nf);
                acc[nf][0] = __builtin_amdgcn_mfma_f32_16x16x32_bf16(A, B0, acc[nf][0], 0, 0, 0);
                acc[nf][1] = __builtin_amdgcn_mfma_f32_16x16x32_bf16(A, B1, acc[nf][1], 0, 0, 0);
                acc[nf][2] = __builtin_amdgcn_mfma_f32_16x16x32_bf16(A, B2, acc[nf][2], 0, 0, 0);
                acc[nf][3] = __builtin_amdgcn_mfma_f32_16x16x32_bf16(A, B3, acc[nf][3], 0, 0, 0);
            }
            __builtin_amdgcn_s_setprio(0);
        };

        // prologue: tile0 staged; tiles 1,2 in regs; masks 0,1 in regs
        stage_write(0, xload(0));
        float4 xc = xload(1), xn = xload(2);
        unsigned mc = mload1(0), mn = mload1(1);
        LGKM0_BARRIER();        // also publishes the LUT

#pragma unroll 1
        for (int kt = 0; kt < NK1; ++kt) {
            float4 xnew = xload(kt + 3);
            unsigned mnew = mload1(kt + 2);
            l1_compute(kt & 1, mc);
            stage_write((kt + 1) & 1, xc);
            xc = xn; xn = xnew; mc = mn; mn = mnew;
            LGKM0_BARRIER();
        }

        epilogueToH(b1);           // H untouched until here
        LGKM0_BARRIER();           // h1 visible
    }

    // ---------------- Layers 2 & 3: barrier-free, masks depth-4 ------------
#pragma unroll 1
    for (int layer = 0; layer < 2; ++layer) {
        const unsigned char* mb = ws + (layer == 0 ? M2_OFF : M3_OFF)
                                + wave * (NK2 * 256) + lane * 4;
        const float* bias = (layer == 0) ? b2 : b3;

        zeroAcc();

        auto mload2 = [&](int t) -> unsigned {
            int tc = t < NK2 ? t : NK2 - 1;
            return *(const unsigned*)(mb + tc * 256);
        };
        auto l23_compute = [&](int kt, unsigned m) {
            // kt*64 overlaps the XOR field -> keep INSIDE the XOR (R7 lesson)
            unsigned hb = (((unsigned)(lr * 1024 + kt * 64 + lg * 16)) ^ swz);
            short8 B0 = *(const short8*)(lds + hb);
            short8 B1 = *(const short8*)(lds + hb + 16384);
            short8 B2 = *(const short8*)(lds + hb + 32768);
            short8 B3 = *(const short8*)(lds + hb + 49152);
            __builtin_amdgcn_s_setprio(1);
#pragma unroll
            for (int nf = 0; nf < 4; ++nf) {
                short8 A = lutA(m, nf);
                acc[nf][0] = __builtin_amdgcn_mfma_f32_16x16x32_bf16(A, B0, acc[nf][0], 0, 0, 0);
                acc[nf][1] = __builtin_amdgcn_mfma_f32_16x16x32_bf16(A, B1, acc[nf][1], 0, 0, 0);
                acc[nf][2] = __builtin_amdgcn_mfma_f32_16x16x32_bf16(A, B2, acc[nf][2], 0, 0, 0);
                acc[nf][3] = __builtin_amdgcn_mfma_f32_16x16x32_bf16(A, B3, acc[nf][3], 0, 0, 0);
            }
            __builtin_amdgcn_s_setprio(0);
        };

        unsigned q0 = mload2(0), q1 = mload2(1), q2 = mload2(2), q3 = mload2(3);
#pragma unroll 1
        for (int kt = 0; kt < NK2; kt += 4) {
            l23_compute(kt + 0, q0); q0 = mload2(kt + 4);
            l23_compute(kt + 1, q1); q1 = mload2(kt + 5);
            l23_compute(kt + 2, q2); q2 = mload2(kt + 6);
            l23_compute(kt + 3, q3); q3 = mload2(kt + 7);
        }

        LGKM0_BARRIER();           // all waves' H reads done before overwrite
        epilogueToH(bias);
        LGKM0_BARRIER();           // new H visible
    }

    // ---------------- Layer 4: h3 @ w4^T (16-col padded, 10 real) ----------
    if (wave < 4) {
        const unsigned char* w4b = ws + W4_OFF + lr * 1024 + lg * 16;
        const int m = wave * 16 + lr;
        short8 w4f[16];
#pragma unroll
        for (int kt = 0; kt < NK2; ++kt)
            w4f[kt] = *(const short8*)(w4b + kt * 64);
        f32x4 acc4 = (f32x4){0.f, 0.f, 0.f, 0.f};
#pragma unroll
        for (int kt = 0; kt < NK2; ++kt) {
            short8 a = *(const short8*)(lds + h_off(m, kt * 64 + lg * 16));
            acc4 = __builtin_amdgcn_mfma_f32_16x16x32_bf16(a, w4f[kt], acc4, 0, 0, 0);
        }
        if (lr < 10) {
            float bv = b4[lr];
#pragma unroll
            for (int r = 0; r < 4; ++r) {
                int row = row_base + wave * 16 + lg * 4 + r;
                out[(size_t)row * 10 + lr] = acc4[r] + bv;
            }
        }
    }
}

extern "C" void kernel_launch(void* const* d_in, const int* in_sizes, int n_in,
                              void* d_out, int out_size, void* d_ws, size_t ws_size,
                              hipStream_t stream) {
    const float* x  = (const float*)d_in[0];
    const float* w1 = (const float*)d_in[1];
    const float* b1 = (const float*)d_in[2];
    const float* w2 = (const float*)d_in[3];
    const float* b2 = (const float*)d_in[4];
    const float* w3 = (const float*)d_in[5];
    const float* b3 = (const float*)d_in[6];
    const float* w4 = (const float*)d_in[7];
    const float* b4 = (const float*)d_in[8];
    float* out = (float*)d_out;
    unsigned char* ws = (unsigned char*)d_ws;

    if (ws_size < (size_t)WS_BYTES) return;

    const int B = in_sizes[0] / K1;           // 65536
    const int nblk = B / BM;                  // 1024

    (void)hipFuncSetAttribute((const void*)fused_mlp,
                              hipFuncAttributeMaxDynamicSharedMemorySize, LDS_TOTAL);

    const int prep_total = 8 * NK1 * 64 + 2 * (8 * NK2 * 64) + 16 * (HID / 16);
    prep_weights<<<(prep_total + 255) / 256, 256, 0, stream>>>(w1, w2, w3, w4, ws);
    fused_mlp<<<nblk, THREADS, LDS_TOTAL, stream>>>(x, ws, b1, b2, b3, b4, out);
}

// Round 14
// 104.822 us; speedup vs baseline: 1.2294x; 1.0098x over previous
//
#include <hip/hip_runtime.h>
#include <hip/hip_bf16.h>
#include <stdint.h>

// ---------------------------------------------------------------------------
// BinaryMLP fused — FINAL (round-11 verified best, 110.0 us).
// Design: binarized weights packed as 1-bit masks (prep kernel), expanded
// in-kernel to bf16 +-1 MFMA A-fragments via a single broadcast 16-entry LDS
// LUT; activations live in a 64x512 bf16 XOR-swizzled LDS tile (H), updated
// in place layer by layer; epilogue via v_cvt_pk_bf16_f32 + ds_write_b64.
// Schedule: L1 per-kt LDS dbuf for x with lgkm-only barriers (vmcnt is NEVER
// drained anywhere); L2/L3 K-loops barrier-free with depth-4 mask prefetch;
// setprio(1) around MFMA clusters. BM=64, 8 waves x (64n x 64b), 2 blocks/CU.
//
// Measured-negative variants (do not retry): 32x32x16 MFMA (R9/R12: same
// LDS-per-FLOP due to fragment reuse, longer dep chains); LUT replication
// (R10: breaks same-address broadcast, 9.3M->17M conflicts); B-register
// double-buffer or depth-4 W prefetch (R4/R10: spills past 128 VGPR ->
// GB-scale scratch traffic); W or x staged via per-K-step LDS + vmcnt(0)
// barriers (R1/R3: barrier drain serializes ~full memory latency per kt).
// XOR-swizzle rule (R7 bug): any offset term overlapping the swizzle bits
// must be applied INSIDE the XOR; (a^s)+d != (a+d)^s when d hits bits 4..6.
// ---------------------------------------------------------------------------

typedef __attribute__((ext_vector_type(8))) short short8;   // 8 bf16
typedef __attribute__((ext_vector_type(4))) float f32x4;    // MFMA accum

#define THREADS 512
#define BM      64
#define HID     512
#define K1      784
#define K1P     800             // 25 K-tiles of 32
#define BK      32
#define NK1     (K1P / BK)      // 25
#define NK2     (HID / BK)      // 16

// mask layout per layer: [wave][kt][lane] dwords (256 B per wave-kt)
#define M1_OFF  0
#define M1_BYTES (8 * NK1 * 256)            // 51200
#define M2_OFF  (M1_OFF + M1_BYTES)
#define M2_BYTES (8 * NK2 * 256)            // 32768
#define M3_OFF  (M2_OFF + M2_BYTES)
#define W4_OFF  (M3_OFF + M2_BYTES)
#define W4_BYTES (16 * HID * 2)             // 16384 (rows 10..15 zero)
#define WS_BYTES (W4_OFF + W4_BYTES)

#define H_BYTES  (BM * HID * 2)             // 65536
#define XBUF0    H_BYTES
#define XTILE_SZ (BM * BK * 2)              // 4096 per K-tile
#define LUT_OFF  (XBUF0 + 2 * XTILE_SZ)     // 73728 (128-aligned)
#define LDS_TOTAL (LUT_OFF + 128)           // 73856 -> 2 blocks/CU

#define LGKM0_BARRIER()  do {                                   \
    asm volatile("s_waitcnt lgkmcnt(0)" ::: "memory");          \
    __builtin_amdgcn_s_barrier();                               \
} while (0)

__device__ __forceinline__ unsigned short bfu(float f) {
    __hip_bfloat16 h = __float2bfloat16(f);
    return *reinterpret_cast<unsigned short*>(&h);
}

__device__ __forceinline__ unsigned cvtpk(float lo, float hi) {
    unsigned d;
    asm("v_cvt_pk_bf16_f32 %0, %1, %2" : "=v"(d) : "v"(lo), "v"(hi));
    return d;
}

// ---------------------------------------------------------------------------
// prep: pack sign bits in per-(wave,kt,lane) fragment order (bit nf*8+j:
// n = wave*64+nf*16+(lane&15), k = kt*32+(lane>>4)*8+j); w4 -> bf16 panel.
// ---------------------------------------------------------------------------
__global__ void prep_weights(const float* __restrict__ w1, const float* __restrict__ w2,
                             const float* __restrict__ w3, const float* __restrict__ w4,
                             unsigned char* __restrict__ ws)
{
    int id = blockIdx.x * blockDim.x + threadIdx.x;
    const int T1 = 8 * NK1 * 64;        // 12800
    const int T2 = 8 * NK2 * 64;        // 8192
    const int T4 = 16 * (HID / 16);     // 512

    if (id < T1) {
        int wn = id / (NK1 * 64), rem = id % (NK1 * 64);
        int kt = rem / 64, lane = rem % 64;
        int lr = lane & 15, lg = lane >> 4;
        unsigned m = 0;
#pragma unroll
        for (int nf = 0; nf < 4; ++nf) {
            int n = wn * 64 + nf * 16 + lr;
#pragma unroll
            for (int j = 0; j < 8; ++j) {
                int k = kt * BK + lg * 8 + j;
                if (k < K1 && w1[n * K1 + k] < 0.0f) m |= 1u << (nf * 8 + j);
            }
        }
        *(unsigned*)(ws + M1_OFF + (size_t)id * 4) = m;
        return;
    }
    id -= T1;
    if (id < 2 * T2) {
        const float* w = (id < T2) ? w2 : w3;
        unsigned base = (id < T2) ? M2_OFF : M3_OFF;
        int iid = (id < T2) ? id : id - T2;
        int wn = iid / (NK2 * 64), rem = iid % (NK2 * 64);
        int kt = rem / 64, lane = rem % 64;
        int lr = lane & 15, lg = lane >> 4;
        unsigned m = 0;
#pragma unroll
        for (int nf = 0; nf < 4; ++nf) {
            int n = wn * 64 + nf * 16 + lr;
#pragma unroll
            for (int j = 0; j < 8; ++j) {
                int k = kt * BK + lg * 8 + j;
                if (w[n * HID + k] < 0.0f) m |= 1u << (nf * 8 + j);
            }
        }
        *(unsigned*)(ws + base + (size_t)iid * 4) = m;
        return;
    }
    id -= 2 * T2;
    if (id < T4) {
        int n = id / (HID / 16), j = id % (HID / 16);
        int kp0 = j * 16;
        unsigned short v[16];
#pragma unroll
        for (int i = 0; i < 16; ++i)
            v[i] = (n < 10) ? bfu(w4[n * HID + kp0 + i]) : 0;
        unsigned off = W4_OFF + n * 1024 + kp0 * 2;   // plain [16][512]
        *(short8*)(ws + off)      = *(short8*)&v[0];
        *(short8*)(ws + off + 16) = *(short8*)&v[8];
    }
}

// ---------------------------------------------------------------------------
// fused MLP: 1 block = 64 batch rows, 8 waves each owning 64 output cols
// ---------------------------------------------------------------------------
__global__ __launch_bounds__(THREADS, 4)
void fused_mlp(const float* __restrict__ x,
               const unsigned char* __restrict__ ws,
               const float* __restrict__ b1, const float* __restrict__ b2,
               const float* __restrict__ b3, const float* __restrict__ b4,
               float* __restrict__ out)
{
    extern __shared__ unsigned char lds[];
    const int tid  = threadIdx.x;
    const int lane = tid & 63;
    const int wave = tid >> 6;           // 0..7 : N-slice of 64 cols
    const int lr   = lane & 15;
    const int lg   = lane >> 4;
    const int row_base = blockIdx.x * BM;
    const unsigned swz = (unsigned)((lr & 7) << 4);

    // sign LUT (SINGLE, broadcast-friendly): nibble -> 4 bf16 (+1/-1), 8 B/entry
    if (tid < 16) {
        unsigned e0 = ((tid & 1) ? 0xBF80u : 0x3F80u)
                    | (((tid & 2) ? 0xBF80u : 0x3F80u) << 16);
        unsigned e1 = ((tid & 4) ? 0xBF80u : 0x3F80u)
                    | (((tid & 8) ? 0xBF80u : 0x3F80u) << 16);
        uint2 e; e.x = e0; e.y = e1;
        *(uint2*)(lds + LUT_OFF + tid * 8) = e;
    }

    // acc[nf][mg]: MFMA tile = (weight cols nf*16, batch rows mg*16).
    // D layout (swapped operands): lane col = batch row (lane&15), lane row
    // quad = 4 consecutive n at n0 = wave*64 + nf*16 + lg*4.
    f32x4 acc[4][4];
    auto zeroAcc = [&]() {
#pragma unroll
        for (int nf = 0; nf < 4; ++nf)
#pragma unroll
            for (int mg = 0; mg < 4; ++mg)
                acc[nf][mg] = (f32x4){0.f, 0.f, 0.f, 0.f};
    };

    auto h_off = [&](int row, int bc) -> unsigned {
        return ((unsigned)(row * 1024 + bc)) ^ (unsigned)((row & 7) << 4);
    };

    // epilogue: relu(acc+bias) -> bf16 pairs (cvt_pk) -> ds_write_b64
    auto epilogueToH = [&](const float* __restrict__ bias) {
#pragma unroll
        for (int nf = 0; nf < 4; ++nf) {
            const int n0 = wave * 64 + nf * 16 + lg * 4;
            float4 bv = *(const float4*)(bias + n0);
#pragma unroll
            for (int mg = 0; mg < 4; ++mg) {
                float v0 = acc[nf][mg][0] + bv.x; v0 = v0 > 0.f ? v0 : 0.f;
                float v1 = acc[nf][mg][1] + bv.y; v1 = v1 > 0.f ? v1 : 0.f;
                float v2 = acc[nf][mg][2] + bv.z; v2 = v2 > 0.f ? v2 : 0.f;
                float v3 = acc[nf][mg][3] + bv.w; v3 = v3 > 0.f ? v3 : 0.f;
                uint2 d; d.x = cvtpk(v0, v1); d.y = cvtpk(v2, v3);
                int row = mg * 16 + lr;
                unsigned off = ((unsigned)(row * 1024 + n0 * 2)) ^ (unsigned)((row & 7) << 4);
                *(uint2*)(lds + off) = d;
            }
        }
    };

    // expand one 8-bit fragment via LUT (2 nibble lookups, broadcast) -> short8
    auto lutA = [&](unsigned m, int nf) -> short8 {
        unsigned lo = (m >> (nf * 8)) & 15u;
        unsigned hi = (m >> (nf * 8 + 4)) & 15u;
        union { short8 s; uint2 d[2]; } r;
        r.d[0] = *(const uint2*)(lds + LUT_OFF + lo * 8);
        r.d[1] = *(const uint2*)(lds + LUT_OFF + hi * 8);
        return r.s;
    };

    // ---------------- Layer 1: x (per-kt LDS dbuf) -> h1 -------------------
    {
        zeroAcc();
        const unsigned char* mb1 = ws + M1_OFF + wave * (NK1 * 256) + lane * 4;
        const int srow = tid >> 3, sq = tid & 7;   // staging: 8 lanes/row
        const float* xrow = x + (size_t)(row_base + srow) * K1;
        const unsigned s_off = (((unsigned)(srow * 64 + sq * 8)) ^ (unsigned)((srow & 7) << 4)) + XBUF0;
        // safe hoist: XOR'd term < 1024; +buf*4096 / +mf*1024 are carry-free
        const unsigned xbase = (((unsigned)(lr * 64 + lg * 16)) ^ swz) + XBUF0;

        auto xload = [&](int t) -> float4 {
            int col = t * BK + sq * 4;
            return (col < K1) ? *(const float4*)(xrow + col)
                              : make_float4(0.f, 0.f, 0.f, 0.f);
        };
        auto stage_write = [&](int buf, float4 v) {
            uint2 pk; pk.x = cvtpk(v.x, v.y); pk.y = cvtpk(v.z, v.w);
            *(uint2*)(lds + s_off + buf * XTILE_SZ) = pk;
        };
        auto mload1 = [&](int t) -> unsigned {
            int tc = t < NK1 ? t : NK1 - 1;
            return *(const unsigned*)(mb1 + tc * 256);
        };
        auto l1_compute = [&](int buf, unsigned m) {
            unsigned xb = xbase + buf * XTILE_SZ;
            short8 B0 = *(const short8*)(lds + xb);
            short8 B1 = *(const short8*)(lds + xb + 1024);
            short8 B2 = *(const short8*)(lds + xb + 2048);
            short8 B3 = *(const short8*)(lds + xb + 3072);
            __builtin_amdgcn_s_setprio(1);
#pragma unroll
            for (int nf = 0; nf < 4; ++nf) {
                short8 A = lutA(m, nf);
                acc[nf][0] = __builtin_amdgcn_mfma_f32_16x16x32_bf16(A, B0, acc[nf][0], 0, 0, 0);
                acc[nf][1] = __builtin_amdgcn_mfma_f32_16x16x32_bf16(A, B1, acc[nf][1], 0, 0, 0);
                acc[nf][2] = __builtin_amdgcn_mfma_f32_16x16x32_bf16(A, B2, acc[nf][2], 0, 0, 0);
                acc[nf][3] = __builtin_amdgcn_mfma_f32_16x16x32_bf16(A, B3, acc[nf][3], 0, 0, 0);
            }
            __builtin_amdgcn_s_setprio(0);
        };

        // prologue: tile0 staged; tiles 1,2 in regs; masks 0,1 in regs
        stage_write(0, xload(0));
        float4 xc = xload(1), xn = xload(2);
        unsigned mc = mload1(0), mn = mload1(1);
        LGKM0_BARRIER();        // also publishes the LUT

#pragma unroll 1
        for (int kt = 0; kt < NK1; ++kt) {
            float4 xnew = xload(kt + 3);
            unsigned mnew = mload1(kt + 2);
            l1_compute(kt & 1, mc);
            stage_write((kt + 1) & 1, xc);
            xc = xn; xn = xnew; mc = mn; mn = mnew;
            LGKM0_BARRIER();
        }

        epilogueToH(b1);           // H untouched until here
        LGKM0_BARRIER();           // h1 visible
    }

    // ---------------- Layers 2 & 3: barrier-free, masks depth-4 ------------
#pragma unroll 1
    for (int layer = 0; layer < 2; ++layer) {
        const unsigned char* mb = ws + (layer == 0 ? M2_OFF : M3_OFF)
                                + wave * (NK2 * 256) + lane * 4;
        const float* bias = (layer == 0) ? b2 : b3;

        zeroAcc();

        auto mload2 = [&](int t) -> unsigned {
            int tc = t < NK2 ? t : NK2 - 1;
            return *(const unsigned*)(mb + tc * 256);
        };
        auto l23_compute = [&](int kt, unsigned m) {
            // kt*64 overlaps the XOR field -> keep INSIDE the XOR (R7 lesson)
            unsigned hb = (((unsigned)(lr * 1024 + kt * 64 + lg * 16)) ^ swz);
            short8 B0 = *(const short8*)(lds + hb);
            short8 B1 = *(const short8*)(lds + hb + 16384);
            short8 B2 = *(const short8*)(lds + hb + 32768);
            short8 B3 = *(const short8*)(lds + hb + 49152);
            __builtin_amdgcn_s_setprio(1);
#pragma unroll
            for (int nf = 0; nf < 4; ++nf) {
                short8 A = lutA(m, nf);
                acc[nf][0] = __builtin_amdgcn_mfma_f32_16x16x32_bf16(A, B0, acc[nf][0], 0, 0, 0);
                acc[nf][1] = __builtin_amdgcn_mfma_f32_16x16x32_bf16(A, B1, acc[nf][1], 0, 0, 0);
                acc[nf][2] = __builtin_amdgcn_mfma_f32_16x16x32_bf16(A, B2, acc[nf][2], 0, 0, 0);
                acc[nf][3] = __builtin_amdgcn_mfma_f32_16x16x32_bf16(A, B3, acc[nf][3], 0, 0, 0);
            }
            __builtin_amdgcn_s_setprio(0);
        };

        unsigned q0 = mload2(0), q1 = mload2(1), q2 = mload2(2), q3 = mload2(3);
#pragma unroll 1
        for (int kt = 0; kt < NK2; kt += 4) {
            l23_compute(kt + 0, q0); q0 = mload2(kt + 4);
            l23_compute(kt + 1, q1); q1 = mload2(kt + 5);
            l23_compute(kt + 2, q2); q2 = mload2(kt + 6);
            l23_compute(kt + 3, q3); q3 = mload2(kt + 7);
        }

        LGKM0_BARRIER();           // all waves' H reads done before overwrite
        epilogueToH(bias);
        LGKM0_BARRIER();           // new H visible
    }

    // ---------------- Layer 4: h3 @ w4^T (16-col padded, 10 real) ----------
    if (wave < 4) {
        const unsigned char* w4b = ws + W4_OFF + lr * 1024 + lg * 16;
        const int m = wave * 16 + lr;
        short8 w4f[16];
#pragma unroll
        for (int kt = 0; kt < NK2; ++kt)
            w4f[kt] = *(const short8*)(w4b + kt * 64);
        f32x4 acc4 = (f32x4){0.f, 0.f, 0.f, 0.f};
#pragma unroll
        for (int kt = 0; kt < NK2; ++kt) {
            short8 a = *(const short8*)(lds + h_off(m, kt * 64 + lg * 16));
            acc4 = __builtin_amdgcn_mfma_f32_16x16x32_bf16(a, w4f[kt], acc4, 0, 0, 0);
        }
        if (lr < 10) {
            float bv = b4[lr];
#pragma unroll
            for (int r = 0; r < 4; ++r) {
                int row = row_base + wave * 16 + lg * 4 + r;
                out[(size_t)row * 10 + lr] = acc4[r] + bv;
            }
        }
    }
}

extern "C" void kernel_launch(void* const* d_in, const int* in_sizes, int n_in,
                              void* d_out, int out_size, void* d_ws, size_t ws_size,
                              hipStream_t stream) {
    const float* x  = (const float*)d_in[0];
    const float* w1 = (const float*)d_in[1];
    const float* b1 = (const float*)d_in[2];
    const float* w2 = (const float*)d_in[3];
    const float* b2 = (const float*)d_in[4];
    const float* w3 = (const float*)d_in[5];
    const float* b3 = (const float*)d_in[6];
    const float* w4 = (const float*)d_in[7];
    const float* b4 = (const float*)d_in[8];
    float* out = (float*)d_out;
    unsigned char* ws = (unsigned char*)d_ws;

    if (ws_size < (size_t)WS_BYTES) return;

    const int B = in_sizes[0] / K1;           // 65536
    const int nblk = B / BM;                  // 1024

    (void)hipFuncSetAttribute((const void*)fused_mlp,
                              hipFuncAttributeMaxDynamicSharedMemorySize, LDS_TOTAL);

    const int prep_total = 8 * NK1 * 64 + 2 * (8 * NK2 * 64) + 16 * (HID / 16);
    prep_weights<<<(prep_total + 255) / 256, 256, 0, stream>>>(w1, w2, w3, w4, ws);
    fused_mlp<<<nblk, THREADS, LDS_TOTAL, stream>>>(x, ws, b1, b2, b3, b4, out);
}